// Round 1
// 4347.992 us; speedup vs baseline: 1.7788x; 1.7788x over previous
//
#include <hip/hip_runtime.h>

#define NHEADS 40
#define HDIM 128
#define SEQ 1024
#define HID 5120
#define KDIM 5120
#define NEG_BIG (-1e30f)

typedef unsigned short u16;
typedef unsigned int u32;
typedef __attribute__((ext_vector_type(8))) short s16x8;   // 8 bf16 (4 VGPRs)
typedef __attribute__((ext_vector_type(4))) float fx4;     // MFMA C/D

// ---------------------------------------------------------------------------
// fp32 -> (hi, lo) bf16 split, RNE. 8 elems/thread/iter, fully vectorized.
// ---------------------------------------------------------------------------
__device__ __forceinline__ u32 f2bf_rne(float f) {
    const u32 u = __float_as_uint(f);
    return (u + 0x7fffu + ((u >> 16) & 1u)) >> 16;
}

__global__ void split_bf16(const float* __restrict__ X, u16* __restrict__ Hh,
                           u16* __restrict__ Ll, long n8) {
    const long stride = (long)gridDim.x * blockDim.x;
    for (long i = (long)blockIdx.x * blockDim.x + threadIdx.x; i < n8; i += stride) {
        const float4 a = ((const float4*)X)[2 * i];
        const float4 b = ((const float4*)X)[2 * i + 1];
        const float f[8] = {a.x, a.y, a.z, a.w, b.x, b.y, b.z, b.w};
        u32 hw[8], lw[8];
#pragma unroll
        for (int j = 0; j < 8; ++j) {
            const u32 hb = f2bf_rne(f[j]);
            const float hf = __uint_as_float(hb << 16);
            hw[j] = hb;
            lw[j] = f2bf_rne(f[j] - hf);
        }
        uint4 ho, lo;
        ho.x = hw[0] | (hw[1] << 16); ho.y = hw[2] | (hw[3] << 16);
        ho.z = hw[4] | (hw[5] << 16); ho.w = hw[6] | (hw[7] << 16);
        lo.x = lw[0] | (lw[1] << 16); lo.y = lw[2] | (lw[3] << 16);
        lo.z = lw[4] | (lw[5] << 16); lo.w = lw[6] | (lw[7] << 16);
        ((uint4*)Hh)[i] = ho;
        ((uint4*)Ll)[i] = lo;
    }
}

// ---------------------------------------------------------------------------
// bf16x3 split-precision GEMM: C = (Ah+Al) * (Bh+Bl)^T, fp32 out.
// A[M,K], B[N,K] both K-contiguous bf16 (hi/lo pairs). 128x128 tile, BK=32,
// 4 waves (2x2), 16x16x32 MFMA, global_load_lds staging, frag-major LDS.
// EPI=0: scatter into Q/K/V [B,NH,S,D] (sec = n/5120). EPI=1: row-major [M,HID].
// ---------------------------------------------------------------------------
__device__ __forceinline__ void gload_lds16(const void* g, void* l) {
    __builtin_amdgcn_global_load_lds(
        (const __attribute__((address_space(1))) void*)g,
        (__attribute__((address_space(3))) void*)l, 16, 0, 0);
}

template <int EPI>
__launch_bounds__(256, 2)
__global__ void gemm3_bt(const u16* __restrict__ Ah, const u16* __restrict__ Al,
                         const u16* __restrict__ Bh, const u16* __restrict__ Bl,
                         float* __restrict__ O0, float* __restrict__ O1,
                         float* __restrict__ O2) {
    // frag-major LDS: fragment f = kb*128 + row holds 8 bf16 (16B) at [f*8].
    __shared__ u16 sAh[4096], sAl[4096], sBh[4096], sBl[4096];

    const int t = threadIdx.x;
    const int lane = t & 63;
    const int w = t >> 6, wm = w >> 1, wn = w & 1;

    // XCD-aware bijective swizzle (nwg % 8 == 0 for both grids used)
    const int nwg = gridDim.x * gridDim.y;
    const int id = blockIdx.y * gridDim.x + blockIdx.x;
    const int v = (id & 7) * (nwg >> 3) + (id >> 3);
    const int nt = v >> 4, mt = v & 15;          // gridDim.y == 16 always
    const int n0 = nt * 128, m0 = mt * 128;

    // staging: 2 fragments per thread per array (512 frags / 256 threads)
    const int f0 = t, f1 = t + 256;
    const int r0 = f0 & 127, c0 = (f0 >> 7) * 8;
    const int r1 = f1 & 127, c1 = (f1 >> 7) * 8;
    const u16* gA0h = Ah + (long)(m0 + r0) * KDIM + c0;
    const u16* gA1h = Ah + (long)(m0 + r1) * KDIM + c1;
    const u16* gA0l = Al + (long)(m0 + r0) * KDIM + c0;
    const u16* gA1l = Al + (long)(m0 + r1) * KDIM + c1;
    const u16* gB0h = Bh + (long)(n0 + r0) * KDIM + c0;
    const u16* gB1h = Bh + (long)(n0 + r1) * KDIM + c1;
    const u16* gB0l = Bl + (long)(n0 + r0) * KDIM + c0;
    const u16* gB1l = Bl + (long)(n0 + r1) * KDIM + c1;
    u16* lA0h = &sAh[f0 * 8]; u16* lA1h = &sAh[f1 * 8];
    u16* lA0l = &sAl[f0 * 8]; u16* lA1l = &sAl[f1 * 8];
    u16* lB0h = &sBh[f0 * 8]; u16* lB1h = &sBh[f1 * 8];
    u16* lB0l = &sBl[f0 * 8]; u16* lB1l = &sBl[f1 * 8];

    // ds_read addressing: A frag mf -> row wm*64+mf*16+(lane&15), kb = lane>>4
    const int kb = lane >> 4;
    const int offA = (kb * 128 + wm * 64 + (lane & 15)) * 8;
    const int offB = (kb * 128 + wn * 64 + (lane & 15)) * 8;

    fx4 acc[4][4] = {};

    for (int k0 = 0; k0 < KDIM; k0 += 32) {
        __syncthreads();                      // previous iter's ds_reads done
        gload_lds16(gA0h + k0, lA0h); gload_lds16(gA1h + k0, lA1h);
        gload_lds16(gA0l + k0, lA0l); gload_lds16(gA1l + k0, lA1l);
        gload_lds16(gB0h + k0, lB0h); gload_lds16(gB1h + k0, lB1h);
        gload_lds16(gB0l + k0, lB0l); gload_lds16(gB1l + k0, lB1l);
        __syncthreads();                      // drains vmcnt(0) before barrier

        s16x8 avh[4], avl[4], bvh[4], bvl[4];
#pragma unroll
        for (int i = 0; i < 4; ++i) {
            avh[i] = *(const s16x8*)&sAh[offA + i * 128];
            avl[i] = *(const s16x8*)&sAl[offA + i * 128];
            bvh[i] = *(const s16x8*)&sBh[offB + i * 128];
            bvl[i] = *(const s16x8*)&sBl[offB + i * 128];
        }
#pragma unroll
        for (int mf = 0; mf < 4; ++mf)
#pragma unroll
            for (int nf = 0; nf < 4; ++nf) {
                fx4 c = acc[mf][nf];
                c = __builtin_amdgcn_mfma_f32_16x16x32_bf16(avh[mf], bvh[nf], c, 0, 0, 0);
                c = __builtin_amdgcn_mfma_f32_16x16x32_bf16(avh[mf], bvl[nf], c, 0, 0, 0);
                c = __builtin_amdgcn_mfma_f32_16x16x32_bf16(avl[mf], bvh[nf], c, 0, 0, 0);
                acc[mf][nf] = c;
            }
    }

    // epilogue. C/D: n = lane&15, m = (lane>>4)*4 + reg  [verified mapping]
    const int sec = (EPI == 0) ? (n0 / HID) : 0;
    float* Ob = (sec == 0) ? O0 : (sec == 1) ? O1 : O2;
    const int nsec0 = n0 - sec * HID;
#pragma unroll
    for (int mf = 0; mf < 4; ++mf) {
        const int mBase = m0 + wm * 64 + mf * 16 + (lane >> 4) * 4;
#pragma unroll
        for (int nf = 0; nf < 4; ++nf) {
            const int nn = nsec0 + wn * 64 + nf * 16 + (lane & 15);
#pragma unroll
            for (int r = 0; r < 4; ++r) {
                const int m = mBase + r;
                const float val = acc[mf][nf][r];
                if (EPI == 0) {
                    const int b = m >> 10, s = m & 1023;
                    const int h = nn >> 7, d = nn & 127;
                    Ob[(((long)(b * NHEADS + h)) * SEQ + s) * HDIM + d] = val;
                } else {
                    O0[(long)m * HID + nn] = val;
                }
            }
        }
    }
}

// ---------------------------------------------------------------------------
// legacy fp32 GEMM (fallback if workspace too small) — unchanged
// ---------------------------------------------------------------------------
template <int EPI>
__launch_bounds__(256)
__global__ void gemm_bt(const float* __restrict__ A, const float* __restrict__ B,
                        float* __restrict__ O0, float* __restrict__ O1,
                        float* __restrict__ O2) {
    __shared__ float lA[32][132];
    __shared__ float lB[32][132];
    const int t = threadIdx.x;
    const int tm = t >> 4, tn = t & 15;
    const int m0 = blockIdx.y * 128, n0 = blockIdx.x * 128;
    const int sr = t >> 3;
    const int sk = (t & 7) * 4;

    float acc[8][8] = {};
    const float* Ag = A + (long)(m0 + sr) * KDIM + sk;
    const float* Bg = B + (long)(n0 + sr) * KDIM + sk;

    for (int k0 = 0; k0 < KDIM; k0 += 32) {
        __syncthreads();
#pragma unroll
        for (int p = 0; p < 4; ++p) {
            const float4 av = *(const float4*)(Ag + (long)p * 32 * KDIM + k0);
            const float4 bv = *(const float4*)(Bg + (long)p * 32 * KDIM + k0);
            const int m = sr + p * 32;
            lA[sk + 0][m] = av.x; lA[sk + 1][m] = av.y;
            lA[sk + 2][m] = av.z; lA[sk + 3][m] = av.w;
            lB[sk + 0][m] = bv.x; lB[sk + 1][m] = bv.y;
            lB[sk + 2][m] = bv.z; lB[sk + 3][m] = bv.w;
        }
        __syncthreads();
#pragma unroll 4
        for (int kk = 0; kk < 32; ++kk) {
            const float4 a0 = *(const float4*)&lA[kk][tm * 4];
            const float4 a1 = *(const float4*)&lA[kk][64 + tm * 4];
            const float4 b0 = *(const float4*)&lB[kk][tn * 4];
            const float4 b1 = *(const float4*)&lB[kk][64 + tn * 4];
            const float ar[8] = {a0.x, a0.y, a0.z, a0.w, a1.x, a1.y, a1.z, a1.w};
            const float br[8] = {b0.x, b0.y, b0.z, b0.w, b1.x, b1.y, b1.z, b1.w};
#pragma unroll
            for (int r = 0; r < 8; ++r)
#pragma unroll
                for (int c = 0; c < 8; ++c) acc[r][c] += ar[r] * br[c];
        }
    }

    const int sec = n0 / HID;
    const int h = (n0 % HID) / HDIM;
#pragma unroll
    for (int r8 = 0; r8 < 8; ++r8) {
        const int mi = m0 + ((r8 < 4) ? (tm * 4 + r8) : (64 + tm * 4 + (r8 - 4)));
        float4 v0, v1;
        v0.x = acc[r8][0]; v0.y = acc[r8][1]; v0.z = acc[r8][2]; v0.w = acc[r8][3];
        v1.x = acc[r8][4]; v1.y = acc[r8][5]; v1.z = acc[r8][6]; v1.w = acc[r8][7];
        if (EPI == 0) {
            const int b = mi >> 10, s = mi & 1023;
            float* Ob = (sec == 0) ? O0 : (sec == 1) ? O1 : O2;
            float* dst = Ob + ((long)(b * NHEADS + h) * SEQ + s) * HDIM;
            *(float4*)(dst + tn * 4) = v0;
            *(float4*)(dst + 64 + tn * 4) = v1;
        } else {
            float* dst = O0 + (long)mi * HID + n0;
            *(float4*)(dst + tn * 4) = v0;
            *(float4*)(dst + 64 + tn * 4) = v1;
        }
    }
}

// ---------------------------------------------------------------------------
// fp32 flash attention w/ ALiBi + causal — unchanged (proven)
// ---------------------------------------------------------------------------
__launch_bounds__(256)
__global__ void attn_fwd(const float* __restrict__ Q, const float* __restrict__ K,
                         const float* __restrict__ V, const float* __restrict__ mask,
                         float* __restrict__ ATT) {
    __shared__ float lQ[128][36];
    __shared__ float lK[128][36];
    __shared__ float lV[32][132];
    __shared__ float lP[32][36];
    __shared__ float lM[SEQ];

    const int t = threadIdx.x;
    const int tm = t >> 4, tn = t & 15;
    const int qt = blockIdx.x, h = blockIdx.y, b = blockIdx.z;
    const int q0 = qt * 32;
    const long bh = (long)b * NHEADS + h;
    const float* Qh = Q + bh * SEQ * HDIM;
    const float* Kh = K + bh * SEQ * HDIM;
    const float* Vh = V + bh * SEQ * HDIM;

    {
        const float* mrow = mask + ((long)h * SEQ + (SEQ - 1)) * SEQ;
#pragma unroll
        for (int p = 0; p < 4; ++p) {
            const int j = t + p * 256;
            lM[j] = fminf(fmaxf(mrow[j], NEG_BIG), 1e30f);
        }
    }
    {
        const int row = t >> 5;
        const int col = (t & 31) * 4;
#pragma unroll
        for (int p = 0; p < 4; ++p) {
            const float4 qv = *(const float4*)(Qh + (long)(q0 + row + p * 8) * HDIM + col);
            lQ[col + 0][row + p * 8] = qv.x; lQ[col + 1][row + p * 8] = qv.y;
            lQ[col + 2][row + p * 8] = qv.z; lQ[col + 3][row + p * 8] = qv.w;
        }
    }

    float O[2][8] = {};
    float mrun[2] = {NEG_BIG, NEG_BIG};
    float lrun[2] = {0.f, 0.f};
    const int i0 = q0 + tm * 2;
    const float scale = 0.08838834764831845f;

    __syncthreads();

    for (int kt = 0; kt <= qt; ++kt) {
        const int kv0 = kt * 32;
        if (kt) __syncthreads();
        {
            const int row = t >> 5;
            const int col = (t & 31) * 4;
#pragma unroll
            for (int p = 0; p < 4; ++p) {
                const float4 kv = *(const float4*)(Kh + (long)(kv0 + row + p * 8) * HDIM + col);
                lK[col + 0][row + p * 8] = kv.x; lK[col + 1][row + p * 8] = kv.y;
                lK[col + 2][row + p * 8] = kv.z; lK[col + 3][row + p * 8] = kv.w;
                const float4 vv = *(const float4*)(Vh + (long)(kv0 + row + p * 8) * HDIM + col);
                *(float4*)&lV[row + p * 8][col] = vv;
            }
        }
        __syncthreads();

        float S00 = 0.f, S01 = 0.f, S10 = 0.f, S11 = 0.f;
#pragma unroll 8
        for (int d = 0; d < 128; ++d) {
            const float2 qa = *(const float2*)&lQ[d][tm * 2];
            const float2 ka = *(const float2*)&lK[d][tn * 2];
            S00 += qa.x * ka.x; S01 += qa.x * ka.y;
            S10 += qa.y * ka.x; S11 += qa.y * ka.y;
        }
        float Sv[2][2] = {{S00, S01}, {S10, S11}};

        float tmax[2] = {NEG_BIG, NEG_BIG};
#pragma unroll
        for (int r = 0; r < 2; ++r)
#pragma unroll
            for (int c = 0; c < 2; ++c) {
                const int j = kv0 + tn * 2 + c;
                float vv = Sv[r][c] * scale + lM[j];
                if (j > i0 + r) vv = NEG_BIG;
                Sv[r][c] = vv;
                tmax[r] = fmaxf(tmax[r], vv);
            }
#pragma unroll
        for (int x = 1; x < 16; x <<= 1) {
            tmax[0] = fmaxf(tmax[0], __shfl_xor(tmax[0], x, 64));
            tmax[1] = fmaxf(tmax[1], __shfl_xor(tmax[1], x, 64));
        }
        float alpha[2], rsum[2] = {0.f, 0.f};
#pragma unroll
        for (int r = 0; r < 2; ++r) {
            const float mnew = fmaxf(mrun[r], tmax[r]);
            alpha[r] = __expf(mrun[r] - mnew);
            mrun[r] = mnew;
        }
#pragma unroll
        for (int r = 0; r < 2; ++r)
#pragma unroll
            for (int c = 0; c < 2; ++c) {
                const float pv = __expf(Sv[r][c] - mrun[r]);
                rsum[r] += pv;
                lP[tn * 2 + c][tm * 2 + r] = pv;
            }
#pragma unroll
        for (int x = 1; x < 16; x <<= 1) {
            rsum[0] += __shfl_xor(rsum[0], x, 64);
            rsum[1] += __shfl_xor(rsum[1], x, 64);
        }
#pragma unroll
        for (int r = 0; r < 2; ++r) lrun[r] = lrun[r] * alpha[r] + rsum[r];
#pragma unroll
        for (int dt = 0; dt < 8; ++dt) { O[0][dt] *= alpha[0]; O[1][dt] *= alpha[1]; }
        __syncthreads();

#pragma unroll 4
        for (int kv = 0; kv < 32; ++kv) {
            const float2 pf = *(const float2*)&lP[kv][tm * 2];
            const float4 va = *(const float4*)&lV[kv][tn * 8];
            const float4 vb = *(const float4*)&lV[kv][tn * 8 + 4];
            O[0][0] += pf.x * va.x; O[0][1] += pf.x * va.y;
            O[0][2] += pf.x * va.z; O[0][3] += pf.x * va.w;
            O[0][4] += pf.x * vb.x; O[0][5] += pf.x * vb.y;
            O[0][6] += pf.x * vb.z; O[0][7] += pf.x * vb.w;
            O[1][0] += pf.y * va.x; O[1][1] += pf.y * va.y;
            O[1][2] += pf.y * va.z; O[1][3] += pf.y * va.w;
            O[1][4] += pf.y * vb.x; O[1][5] += pf.y * vb.y;
            O[1][6] += pf.y * vb.z; O[1][7] += pf.y * vb.w;
        }
    }

    const float inv0 = 1.f / lrun[0], inv1 = 1.f / lrun[1];
    float* dst0 = ATT + (long)(b * SEQ + i0 + 0) * HID + h * HDIM + tn * 8;
    float* dst1 = ATT + (long)(b * SEQ + i0 + 1) * HID + h * HDIM + tn * 8;
    float4 o;
    o.x = O[0][0] * inv0; o.y = O[0][1] * inv0; o.z = O[0][2] * inv0; o.w = O[0][3] * inv0;
    *(float4*)dst0 = o;
    o.x = O[0][4] * inv0; o.y = O[0][5] * inv0; o.z = O[0][6] * inv0; o.w = O[0][7] * inv0;
    *(float4*)(dst0 + 4) = o;
    o.x = O[1][0] * inv1; o.y = O[1][1] * inv1; o.z = O[1][2] * inv1; o.w = O[1][3] * inv1;
    *(float4*)dst1 = o;
    o.x = O[1][4] * inv1; o.y = O[1][5] * inv1; o.z = O[1][6] * inv1; o.w = O[1][7] * inv1;
    *(float4*)(dst1 + 4) = o;
}

// ---------------------------------------------------------------------------
extern "C" void kernel_launch(void* const* d_in, const int* in_sizes, int n_in,
                              void* d_out, int out_size, void* d_ws, size_t ws_size,
                              hipStream_t stream) {
    const float* hid  = (const float*)d_in[0];  // [2,1024,5120]
    const float* mask = (const float*)d_in[1];  // [40,1024,1024]
    const float* wpk  = (const float*)d_in[2];  // [15360,5120]
    const float* opr  = (const float*)d_in[3];  // [5120,5120]
    float* out = (float*)d_out;                 // [2,1024,5120]

    const size_t SZF = (size_t)2 * NHEADS * SEQ * HDIM;  // 10,485,760 floats
    const size_t EA = (size_t)2048 * 5120;               // hidden elems
    const size_t EW = (size_t)5120 * 5120;               // one W section elems
    char* ws = (char*)d_ws;
    float* Qb = (float*)ws;
    float* Kb = Qb + SZF;
    float* Vb = Kb + SZF;
    float* At = Vb + SZF;
    const size_t baseB = SZF * 4 * 4;                    // 167.8 MB fp32 region
    u16* Ahh = (u16*)(ws + baseB);                       // hidden hi
    u16* Ahl = Ahh + EA;                                 // hidden lo
    u16* Wh  = (u16*)(ws + baseB + 2 * EA * 2);          // W split region

    const size_t needSec  = baseB + 2 * EA * 2 + 2 * EW * 2;  // ~300 MB
    const size_t needFull = baseB + 2 * EA * 2 + 6 * EW * 2;  // ~500 MB

    if (ws_size >= needSec) {
        const bool full = (ws_size >= needFull);
        split_bf16<<<1024, 256, 0, stream>>>(hid, Ahh, Ahl, (long)(EA / 8));
        if (full) {
            u16* Wl = Wh + 3 * EW;
            split_bf16<<<2048, 256, 0, stream>>>(wpk, Wh, Wl, (long)(3 * EW / 8));
            gemm3_bt<0><<<dim3(120, 16), 256, 0, stream>>>(Ahh, Ahl, Wh, Wl, Qb, Kb, Vb);
        } else {
            u16* Wl = Wh + EW;
            for (int s = 0; s < 3; ++s) {
                split_bf16<<<2048, 256, 0, stream>>>(wpk + s * EW, Wh, Wl, (long)(EW / 8));
                float* Ob = (s == 0) ? Qb : (s == 1) ? Kb : Vb;
                gemm3_bt<0><<<dim3(40, 16), 256, 0, stream>>>(Ahh, Ahl, Wh, Wl, Ob, Ob, Ob);
            }
        }
        attn_fwd<<<dim3(32, NHEADS, 2), 256, 0, stream>>>(Qb, Kb, Vb, mask, At);
        // reuse: Ath/Atl alias hidden split; Oph/Opl alias W split (both dead)
        u16* Ath = Ahh; u16* Atl = Ahl;
        u16* Oph = Wh;  u16* Opl = Wh + EW;
        split_bf16<<<1024, 256, 0, stream>>>(At, Ath, Atl, (long)(EA / 8));
        split_bf16<<<2048, 256, 0, stream>>>(opr, Oph, Opl, (long)(EW / 8));
        gemm3_bt<1><<<dim3(40, 16), 256, 0, stream>>>(Ath, Atl, Oph, Opl, out,
                                                      nullptr, nullptr);
    } else {
        // legacy fp32 path (workspace too small for bf16x3 splits)
        gemm_bt<0><<<dim3(120, 16), 256, 0, stream>>>(hid, wpk, Qb, Kb, Vb);
        attn_fwd<<<dim3(32, NHEADS, 2), 256, 0, stream>>>(Qb, Kb, Vb, mask, At);
        gemm_bt<1><<<dim3(40, 16), 256, 0, stream>>>(At, opr, out, nullptr, nullptr);
    }
}

// Round 2
// 4133.503 us; speedup vs baseline: 1.8711x; 1.0519x over previous
//
#include <hip/hip_runtime.h>

#define NHEADS 40
#define HDIM 128
#define SEQ 1024
#define HID 5120
#define KDIM 5120
#define NEG_BIG (-1e30f)

typedef unsigned short u16;
typedef unsigned int u32;
typedef __attribute__((ext_vector_type(8))) short s16x8;   // 8 bf16 (4 VGPRs)
typedef __attribute__((ext_vector_type(4))) float fx4;     // MFMA C/D

// ---------------------------------------------------------------------------
// fp32 -> (hi, lo) bf16 split, RNE. 8 elems/thread/iter, fully vectorized.
// ---------------------------------------------------------------------------
__device__ __forceinline__ u32 f2bf_rne(float f) {
    const u32 u = __float_as_uint(f);
    return (u + 0x7fffu + ((u >> 16) & 1u)) >> 16;
}

__global__ void split_bf16(const float* __restrict__ X, u16* __restrict__ Hh,
                           u16* __restrict__ Ll, long n8) {
    const long stride = (long)gridDim.x * blockDim.x;
    for (long i = (long)blockIdx.x * blockDim.x + threadIdx.x; i < n8; i += stride) {
        const float4 a = ((const float4*)X)[2 * i];
        const float4 b = ((const float4*)X)[2 * i + 1];
        const float f[8] = {a.x, a.y, a.z, a.w, b.x, b.y, b.z, b.w};
        u32 hw[8], lw[8];
#pragma unroll
        for (int j = 0; j < 8; ++j) {
            const u32 hb = f2bf_rne(f[j]);
            const float hf = __uint_as_float(hb << 16);
            hw[j] = hb;
            lw[j] = f2bf_rne(f[j] - hf);
        }
        uint4 ho, lo;
        ho.x = hw[0] | (hw[1] << 16); ho.y = hw[2] | (hw[3] << 16);
        ho.z = hw[4] | (hw[5] << 16); ho.w = hw[6] | (hw[7] << 16);
        lo.x = lw[0] | (lw[1] << 16); lo.y = lw[2] | (lw[3] << 16);
        lo.z = lw[4] | (lw[5] << 16); lo.w = lw[6] | (lw[7] << 16);
        ((uint4*)Hh)[i] = ho;
        ((uint4*)Ll)[i] = lo;
    }
}

// ---------------------------------------------------------------------------
// bf16x3 split-precision GEMM: C = (Ah+Al) * (Bh+Bl)^T, fp32 out.
// 128x128 tile, BK=32, 4 waves, 16x16x32 MFMA, frag-major LDS (0 conflicts),
// DOUBLE-BUFFERED with 1-deep global_load_lds prefetch (T3 minimum 2-phase):
// issue next tile's loads at top of iter, single vmcnt-drain+barrier at end.
// EPI=0: scatter into Q/K/V [B,NH,S,D]. EPI=1: row-major [M,HID].
// ---------------------------------------------------------------------------
__device__ __forceinline__ void gload_lds16(const void* g, void* l) {
    __builtin_amdgcn_global_load_lds(
        (const __attribute__((address_space(1))) void*)g,
        (__attribute__((address_space(3))) void*)l, 16, 0, 0);
}

template <int EPI>
__launch_bounds__(256, 2)
__global__ void gemm3_bt(const u16* __restrict__ Ah, const u16* __restrict__ Al,
                         const u16* __restrict__ Bh, const u16* __restrict__ Bl,
                         float* __restrict__ O0, float* __restrict__ O1,
                         float* __restrict__ O2) {
    // frag-major: fragment f = kb*128 + row holds 8 bf16 (16B) at [f*8].
    __shared__ u16 sAh[2][4096], sAl[2][4096], sBh[2][4096], sBl[2][4096]; // 64 KB

    const int t = threadIdx.x;
    const int lane = t & 63;
    const int w = t >> 6, wm = w >> 1, wn = w & 1;

    // XCD-aware bijective swizzle (nwg % 8 == 0 for both grids used)
    const int nwg = gridDim.x * gridDim.y;
    const int id = blockIdx.y * gridDim.x + blockIdx.x;
    const int v = (id & 7) * (nwg >> 3) + (id >> 3);
    const int nt = v >> 4, mt = v & 15;          // gridDim.y == 16 always
    const int n0 = nt * 128, m0 = mt * 128;

    // staging: 2 fragments per thread per array (512 frags / 256 threads)
    const int f0 = t, f1 = t + 256;
    const int r0 = f0 & 127, c0 = (f0 >> 7) * 8;
    const int r1 = f1 & 127, c1 = (f1 >> 7) * 8;
    const u16* gA0h = Ah + (long)(m0 + r0) * KDIM + c0;
    const u16* gA1h = Ah + (long)(m0 + r1) * KDIM + c1;
    const u16* gA0l = Al + (long)(m0 + r0) * KDIM + c0;
    const u16* gA1l = Al + (long)(m0 + r1) * KDIM + c1;
    const u16* gB0h = Bh + (long)(n0 + r0) * KDIM + c0;
    const u16* gB1h = Bh + (long)(n0 + r1) * KDIM + c1;
    const u16* gB0l = Bl + (long)(n0 + r0) * KDIM + c0;
    const u16* gB1l = Bl + (long)(n0 + r1) * KDIM + c1;

    // ds_read addressing: A frag mf -> row wm*64+mf*16+(lane&15), kb = lane>>4
    const int kb = lane >> 4;
    const int offA = (kb * 128 + wm * 64 + (lane & 15)) * 8;
    const int offB = (kb * 128 + wn * 64 + (lane & 15)) * 8;

    fx4 acc[4][4] = {};

#define STAGE3(buf, k0off) do {                                            \
        gload_lds16(gA0h + (k0off), &sAh[buf][f0 * 8]);                    \
        gload_lds16(gA1h + (k0off), &sAh[buf][f1 * 8]);                    \
        gload_lds16(gA0l + (k0off), &sAl[buf][f0 * 8]);                    \
        gload_lds16(gA1l + (k0off), &sAl[buf][f1 * 8]);                    \
        gload_lds16(gB0h + (k0off), &sBh[buf][f0 * 8]);                    \
        gload_lds16(gB1h + (k0off), &sBh[buf][f1 * 8]);                    \
        gload_lds16(gB0l + (k0off), &sBl[buf][f0 * 8]);                    \
        gload_lds16(gB1l + (k0off), &sBl[buf][f1 * 8]);                    \
    } while (0)

    // prologue: fill buffer 0, full drain
    STAGE3(0, 0);
    __syncthreads();

    int cur = 0;
    for (int k0 = 0; k0 < KDIM; k0 += 32) {
        // issue next tile's loads into the other buffer (safe: all waves
        // finished reading it before the barrier we just passed)
        if (k0 + 32 < KDIM) {
            if (cur == 0) STAGE3(1, k0 + 32); else STAGE3(0, k0 + 32);
        }

        s16x8 avh[4], avl[4], bvh[4], bvl[4];
#pragma unroll
        for (int i = 0; i < 4; ++i) {
            avh[i] = *(const s16x8*)&sAh[cur][offA + i * 128];
            avl[i] = *(const s16x8*)&sAl[cur][offA + i * 128];
            bvh[i] = *(const s16x8*)&sBh[cur][offB + i * 128];
            bvl[i] = *(const s16x8*)&sBl[cur][offB + i * 128];
        }
        __builtin_amdgcn_s_setprio(1);
#pragma unroll
        for (int mf = 0; mf < 4; ++mf)
#pragma unroll
            for (int nf = 0; nf < 4; ++nf) {
                fx4 c = acc[mf][nf];
                c = __builtin_amdgcn_mfma_f32_16x16x32_bf16(avh[mf], bvh[nf], c, 0, 0, 0);
                c = __builtin_amdgcn_mfma_f32_16x16x32_bf16(avh[mf], bvl[nf], c, 0, 0, 0);
                c = __builtin_amdgcn_mfma_f32_16x16x32_bf16(avl[mf], bvh[nf], c, 0, 0, 0);
                acc[mf][nf] = c;
            }
        __builtin_amdgcn_s_setprio(0);
        // single drain+barrier per K-tile: lands the prefetch, protects buffers
        __syncthreads();
        cur ^= 1;
    }
#undef STAGE3

    // epilogue. C/D: n = lane&15, m = (lane>>4)*4 + reg  [verified mapping]
    const int sec = (EPI == 0) ? (n0 / HID) : 0;
    float* Ob = (sec == 0) ? O0 : (sec == 1) ? O1 : O2;
    const int nsec0 = n0 - sec * HID;
#pragma unroll
    for (int mf = 0; mf < 4; ++mf) {
        const int mBase = m0 + wm * 64 + mf * 16 + (lane >> 4) * 4;
#pragma unroll
        for (int nf = 0; nf < 4; ++nf) {
            const int nn = nsec0 + wn * 64 + nf * 16 + (lane & 15);
#pragma unroll
            for (int r = 0; r < 4; ++r) {
                const int m = mBase + r;
                const float val = acc[mf][nf][r];
                if (EPI == 0) {
                    const int b = m >> 10, s = m & 1023;
                    const int h = nn >> 7, d = nn & 127;
                    Ob[(((long)(b * NHEADS + h)) * SEQ + s) * HDIM + d] = val;
                } else {
                    O0[(long)m * HID + nn] = val;
                }
            }
        }
    }
}

// ---------------------------------------------------------------------------
// legacy fp32 GEMM (fallback if workspace too small) — unchanged
// ---------------------------------------------------------------------------
template <int EPI>
__launch_bounds__(256)
__global__ void gemm_bt(const float* __restrict__ A, const float* __restrict__ B,
                        float* __restrict__ O0, float* __restrict__ O1,
                        float* __restrict__ O2) {
    __shared__ float lA[32][132];
    __shared__ float lB[32][132];
    const int t = threadIdx.x;
    const int tm = t >> 4, tn = t & 15;
    const int m0 = blockIdx.y * 128, n0 = blockIdx.x * 128;
    const int sr = t >> 3;
    const int sk = (t & 7) * 4;

    float acc[8][8] = {};
    const float* Ag = A + (long)(m0 + sr) * KDIM + sk;
    const float* Bg = B + (long)(n0 + sr) * KDIM + sk;

    for (int k0 = 0; k0 < KDIM; k0 += 32) {
        __syncthreads();
#pragma unroll
        for (int p = 0; p < 4; ++p) {
            const float4 av = *(const float4*)(Ag + (long)p * 32 * KDIM + k0);
            const float4 bv = *(const float4*)(Bg + (long)p * 32 * KDIM + k0);
            const int m = sr + p * 32;
            lA[sk + 0][m] = av.x; lA[sk + 1][m] = av.y;
            lA[sk + 2][m] = av.z; lA[sk + 3][m] = av.w;
            lB[sk + 0][m] = bv.x; lB[sk + 1][m] = bv.y;
            lB[sk + 2][m] = bv.z; lB[sk + 3][m] = bv.w;
        }
        __syncthreads();
#pragma unroll 4
        for (int kk = 0; kk < 32; ++kk) {
            const float4 a0 = *(const float4*)&lA[kk][tm * 4];
            const float4 a1 = *(const float4*)&lA[kk][64 + tm * 4];
            const float4 b0 = *(const float4*)&lB[kk][tn * 4];
            const float4 b1 = *(const float4*)&lB[kk][64 + tn * 4];
            const float ar[8] = {a0.x, a0.y, a0.z, a0.w, a1.x, a1.y, a1.z, a1.w};
            const float br[8] = {b0.x, b0.y, b0.z, b0.w, b1.x, b1.y, b1.z, b1.w};
#pragma unroll
            for (int r = 0; r < 8; ++r)
#pragma unroll
                for (int c = 0; c < 8; ++c) acc[r][c] += ar[r] * br[c];
        }
    }

    const int sec = n0 / HID;
    const int h = (n0 % HID) / HDIM;
#pragma unroll
    for (int r8 = 0; r8 < 8; ++r8) {
        const int mi = m0 + ((r8 < 4) ? (tm * 4 + r8) : (64 + tm * 4 + (r8 - 4)));
        float4 v0, v1;
        v0.x = acc[r8][0]; v0.y = acc[r8][1]; v0.z = acc[r8][2]; v0.w = acc[r8][3];
        v1.x = acc[r8][4]; v1.y = acc[r8][5]; v1.z = acc[r8][6]; v1.w = acc[r8][7];
        if (EPI == 0) {
            const int b = mi >> 10, s = mi & 1023;
            float* Ob = (sec == 0) ? O0 : (sec == 1) ? O1 : O2;
            float* dst = Ob + ((long)(b * NHEADS + h) * SEQ + s) * HDIM;
            *(float4*)(dst + tn * 4) = v0;
            *(float4*)(dst + 64 + tn * 4) = v1;
        } else {
            float* dst = O0 + (long)mi * HID + n0;
            *(float4*)(dst + tn * 4) = v0;
            *(float4*)(dst + 64 + tn * 4) = v1;
        }
    }
}

// ---------------------------------------------------------------------------
// fp32 flash attention w/ ALiBi + causal — unchanged (proven)
// ---------------------------------------------------------------------------
__launch_bounds__(256)
__global__ void attn_fwd(const float* __restrict__ Q, const float* __restrict__ K,
                         const float* __restrict__ V, const float* __restrict__ mask,
                         float* __restrict__ ATT) {
    __shared__ float lQ[128][36];
    __shared__ float lK[128][36];
    __shared__ float lV[32][132];
    __shared__ float lP[32][36];
    __shared__ float lM[SEQ];

    const int t = threadIdx.x;
    const int tm = t >> 4, tn = t & 15;
    const int qt = blockIdx.x, h = blockIdx.y, b = blockIdx.z;
    const int q0 = qt * 32;
    const long bh = (long)b * NHEADS + h;
    const float* Qh = Q + bh * SEQ * HDIM;
    const float* Kh = K + bh * SEQ * HDIM;
    const float* Vh = V + bh * SEQ * HDIM;

    {
        const float* mrow = mask + ((long)h * SEQ + (SEQ - 1)) * SEQ;
#pragma unroll
        for (int p = 0; p < 4; ++p) {
            const int j = t + p * 256;
            lM[j] = fminf(fmaxf(mrow[j], NEG_BIG), 1e30f);
        }
    }
    {
        const int row = t >> 5;
        const int col = (t & 31) * 4;
#pragma unroll
        for (int p = 0; p < 4; ++p) {
            const float4 qv = *(const float4*)(Qh + (long)(q0 + row + p * 8) * HDIM + col);
            lQ[col + 0][row + p * 8] = qv.x; lQ[col + 1][row + p * 8] = qv.y;
            lQ[col + 2][row + p * 8] = qv.z; lQ[col + 3][row + p * 8] = qv.w;
        }
    }

    float O[2][8] = {};
    float mrun[2] = {NEG_BIG, NEG_BIG};
    float lrun[2] = {0.f, 0.f};
    const int i0 = q0 + tm * 2;
    const float scale = 0.08838834764831845f;

    __syncthreads();

    for (int kt = 0; kt <= qt; ++kt) {
        const int kv0 = kt * 32;
        if (kt) __syncthreads();
        {
            const int row = t >> 5;
            const int col = (t & 31) * 4;
#pragma unroll
            for (int p = 0; p < 4; ++p) {
                const float4 kv = *(const float4*)(Kh + (long)(kv0 + row + p * 8) * HDIM + col);
                lK[col + 0][row + p * 8] = kv.x; lK[col + 1][row + p * 8] = kv.y;
                lK[col + 2][row + p * 8] = kv.z; lK[col + 3][row + p * 8] = kv.w;
                const float4 vv = *(const float4*)(Vh + (long)(kv0 + row + p * 8) * HDIM + col);
                *(float4*)&lV[row + p * 8][col] = vv;
            }
        }
        __syncthreads();

        float S00 = 0.f, S01 = 0.f, S10 = 0.f, S11 = 0.f;
#pragma unroll 8
        for (int d = 0; d < 128; ++d) {
            const float2 qa = *(const float2*)&lQ[d][tm * 2];
            const float2 ka = *(const float2*)&lK[d][tn * 2];
            S00 += qa.x * ka.x; S01 += qa.x * ka.y;
            S10 += qa.y * ka.x; S11 += qa.y * ka.y;
        }
        float Sv[2][2] = {{S00, S01}, {S10, S11}};

        float tmax[2] = {NEG_BIG, NEG_BIG};
#pragma unroll
        for (int r = 0; r < 2; ++r)
#pragma unroll
            for (int c = 0; c < 2; ++c) {
                const int j = kv0 + tn * 2 + c;
                float vv = Sv[r][c] * scale + lM[j];
                if (j > i0 + r) vv = NEG_BIG;
                Sv[r][c] = vv;
                tmax[r] = fmaxf(tmax[r], vv);
            }
#pragma unroll
        for (int x = 1; x < 16; x <<= 1) {
            tmax[0] = fmaxf(tmax[0], __shfl_xor(tmax[0], x, 64));
            tmax[1] = fmaxf(tmax[1], __shfl_xor(tmax[1], x, 64));
        }
        float alpha[2], rsum[2] = {0.f, 0.f};
#pragma unroll
        for (int r = 0; r < 2; ++r) {
            const float mnew = fmaxf(mrun[r], tmax[r]);
            alpha[r] = __expf(mrun[r] - mnew);
            mrun[r] = mnew;
        }
#pragma unroll
        for (int r = 0; r < 2; ++r)
#pragma unroll
            for (int c = 0; c < 2; ++c) {
                const float pv = __expf(Sv[r][c] - mrun[r]);
                rsum[r] += pv;
                lP[tn * 2 + c][tm * 2 + r] = pv;
            }
#pragma unroll
        for (int x = 1; x < 16; x <<= 1) {
            rsum[0] += __shfl_xor(rsum[0], x, 64);
            rsum[1] += __shfl_xor(rsum[1], x, 64);
        }
#pragma unroll
        for (int r = 0; r < 2; ++r) lrun[r] = lrun[r] * alpha[r] + rsum[r];
#pragma unroll
        for (int dt = 0; dt < 8; ++dt) { O[0][dt] *= alpha[0]; O[1][dt] *= alpha[1]; }
        __syncthreads();

#pragma unroll 4
        for (int kv = 0; kv < 32; ++kv) {
            const float2 pf = *(const float2*)&lP[kv][tm * 2];
            const float4 va = *(const float4*)&lV[kv][tn * 8];
            const float4 vb = *(const float4*)&lV[kv][tn * 8 + 4];
            O[0][0] += pf.x * va.x; O[0][1] += pf.x * va.y;
            O[0][2] += pf.x * va.z; O[0][3] += pf.x * va.w;
            O[0][4] += pf.x * vb.x; O[0][5] += pf.x * vb.y;
            O[0][6] += pf.x * vb.z; O[0][7] += pf.x * vb.w;
            O[1][0] += pf.y * va.x; O[1][1] += pf.y * va.y;
            O[1][2] += pf.y * va.z; O[1][3] += pf.y * va.w;
            O[1][4] += pf.y * vb.x; O[1][5] += pf.y * vb.y;
            O[1][6] += pf.y * vb.z; O[1][7] += pf.y * vb.w;
        }
    }

    const float inv0 = 1.f / lrun[0], inv1 = 1.f / lrun[1];
    float* dst0 = ATT + (long)(b * SEQ + i0 + 0) * HID + h * HDIM + tn * 8;
    float* dst1 = ATT + (long)(b * SEQ + i0 + 1) * HID + h * HDIM + tn * 8;
    float4 o;
    o.x = O[0][0] * inv0; o.y = O[0][1] * inv0; o.z = O[0][2] * inv0; o.w = O[0][3] * inv0;
    *(float4*)dst0 = o;
    o.x = O[0][4] * inv0; o.y = O[0][5] * inv0; o.z = O[0][6] * inv0; o.w = O[0][7] * inv0;
    *(float4*)(dst0 + 4) = o;
    o.x = O[1][0] * inv1; o.y = O[1][1] * inv1; o.z = O[1][2] * inv1; o.w = O[1][3] * inv1;
    *(float4*)dst1 = o;
    o.x = O[1][4] * inv1; o.y = O[1][5] * inv1; o.z = O[1][6] * inv1; o.w = O[1][7] * inv1;
    *(float4*)(dst1 + 4) = o;
}

// ---------------------------------------------------------------------------
extern "C" void kernel_launch(void* const* d_in, const int* in_sizes, int n_in,
                              void* d_out, int out_size, void* d_ws, size_t ws_size,
                              hipStream_t stream) {
    const float* hid  = (const float*)d_in[0];  // [2,1024,5120]
    const float* mask = (const float*)d_in[1];  // [40,1024,1024]
    const float* wpk  = (const float*)d_in[2];  // [15360,5120]
    const float* opr  = (const float*)d_in[3];  // [5120,5120]
    float* out = (float*)d_out;                 // [2,1024,5120]

    const size_t SZF = (size_t)2 * NHEADS * SEQ * HDIM;  // 10,485,760 floats
    const size_t EA = (size_t)2048 * 5120;               // hidden elems
    const size_t EW = (size_t)5120 * 5120;               // one W section elems
    char* ws = (char*)d_ws;
    float* Qb = (float*)ws;
    float* Kb = Qb + SZF;
    float* Vb = Kb + SZF;
    float* At = Vb + SZF;
    const size_t baseB = SZF * 4 * 4;                    // 167.8 MB fp32 region
    u16* Ahh = (u16*)(ws + baseB);                       // hidden hi
    u16* Ahl = Ahh + EA;                                 // hidden lo
    u16* Wh  = (u16*)(ws + baseB + 2 * EA * 2);          // W split region

    const size_t needSec  = baseB + 2 * EA * 2 + 2 * EW * 2;  // ~300 MB
    const size_t needFull = baseB + 2 * EA * 2 + 6 * EW * 2;  // ~500 MB

    if (ws_size >= needSec) {
        const bool full = (ws_size >= needFull);
        split_bf16<<<1024, 256, 0, stream>>>(hid, Ahh, Ahl, (long)(EA / 8));
        if (full) {
            u16* Wl = Wh + 3 * EW;
            split_bf16<<<2048, 256, 0, stream>>>(wpk, Wh, Wl, (long)(3 * EW / 8));
            gemm3_bt<0><<<dim3(120, 16), 256, 0, stream>>>(Ahh, Ahl, Wh, Wl, Qb, Kb, Vb);
        } else {
            u16* Wl = Wh + EW;
            for (int s = 0; s < 3; ++s) {
                split_bf16<<<2048, 256, 0, stream>>>(wpk + s * EW, Wh, Wl, (long)(EW / 8));
                float* Ob = (s == 0) ? Qb : (s == 1) ? Kb : Vb;
                gemm3_bt<0><<<dim3(40, 16), 256, 0, stream>>>(Ahh, Ahl, Wh, Wl, Ob, Ob, Ob);
            }
        }
        attn_fwd<<<dim3(32, NHEADS, 2), 256, 0, stream>>>(Qb, Kb, Vb, mask, At);
        // reuse: Ath/Atl alias hidden split; Oph/Opl alias W split (both dead)
        u16* Ath = Ahh; u16* Atl = Ahl;
        u16* Oph = Wh;  u16* Opl = Wh + EW;
        split_bf16<<<1024, 256, 0, stream>>>(At, Ath, Atl, (long)(EA / 8));
        split_bf16<<<2048, 256, 0, stream>>>(opr, Oph, Opl, (long)(EW / 8));
        gemm3_bt<1><<<dim3(40, 16), 256, 0, stream>>>(Ath, Atl, Oph, Opl, out,
                                                      nullptr, nullptr);
    } else {
        // legacy fp32 path (workspace too small for bf16x3 splits)
        gemm_bt<0><<<dim3(120, 16), 256, 0, stream>>>(hid, wpk, Qb, Kb, Vb);
        attn_fwd<<<dim3(32, NHEADS, 2), 256, 0, stream>>>(Qb, Kb, Vb, mask, At);
        gemm_bt<1><<<dim3(40, 16), 256, 0, stream>>>(At, opr, out, nullptr, nullptr);
    }
}